// Round 4
// baseline (3050.462 us; speedup 1.0000x reference)
//
#include <hip/hip_runtime.h>
#include <hip/hip_bf16.h>
#include <hip/hip_cooperative_groups.h>
#include <stdint.h>

namespace cg = cooperative_groups;

#define B_ 32
#define L_ 128
#define H_ 512
#define E_ 256
#define V_ 32000
#define G4 2048   /* 4*H */

typedef __attribute__((ext_vector_type(8))) short short8;
typedef __attribute__((ext_vector_type(4))) float f32x4;

__device__ __forceinline__ short f2bf(float f){
  uint32_t u = __builtin_bit_cast(uint32_t, f);
  u += 0x7FFFu + ((u >> 16) & 1u);           // RNE
  return (short)(u >> 16);
}
__device__ __forceinline__ short8 ld8f_bf(const float* p){
  const f32x4* q = (const f32x4*)p;
  f32x4 a = q[0], b = q[1];
  short8 r;
  r[0]=f2bf(a[0]); r[1]=f2bf(a[1]); r[2]=f2bf(a[2]); r[3]=f2bf(a[3]);
  r[4]=f2bf(b[0]); r[5]=f2bf(b[1]); r[6]=f2bf(b[2]); r[7]=f2bf(b[3]);
  return r;
}
__device__ __forceinline__ f32x4 mfma16(short8 a, short8 b, f32x4 c){
  return __builtin_amdgcn_mfma_f32_16x16x32_bf16(a, b, c, 0, 0, 0);
}
__device__ __forceinline__ float sigm(float x){
  x = fminf(30.f, fmaxf(-30.f, x));
  return 1.f / (1.f + __expf(-x));
}
__device__ __forceinline__ float tanh_f(float x){
  x = fminf(15.f, fmaxf(-15.f, x));
  float e = __expf(-2.f * x);
  return (1.f - e) / (1.f + e);
}

// ---------------------------------------------------------------- init/cast
__global__ void k_init(const float* __restrict__ wout, short* __restrict__ wob,
                       short* __restrict__ h1buf, float* __restrict__ row_sum)
{
  const int stride = gridDim.x * blockDim.x;
  const int tid0 = blockIdx.x * blockDim.x + threadIdx.x;
  if (wob){
    for (int i = tid0; i < V_ * H_ / 8; i += stride)
      *(short8*)(wob + (size_t)i * 8) = ld8f_bf(wout + (size_t)i * 8);
  }
  for (int i = tid0; i < 2 * B_ * H_; i += stride) h1buf[i] = 0;
  for (int i = tid0; i < B_ * L_; i += stride) row_sum[i] = 0.f;
}

// ------------------------------------------- xW1 = embed @ w_ih1^T + biases
// rows r = t*32 + b, M=4096, N=2048, K=256
__global__ __launch_bounds__(256) void k_xw1(const int* __restrict__ gt,
    const float* __restrict__ emb, const float* __restrict__ w_ih1,
    const float* __restrict__ b_ih1, const float* __restrict__ b_hh1,
    float* __restrict__ xW1)
{
  const int wave = (blockIdx.x << 2) + (threadIdx.x >> 6);
  const int lane = threadIdx.x & 63, l15 = lane & 15, lg = lane >> 4;
  const int mt = wave >> 5, n0 = (wave & 31) * 64;
  const int r = mt * 16 + l15;
  const int tt = r >> 5, bb = r & 31;
  const int tok = (tt == 0) ? 0 : gt[bb * L_ + tt - 1];
  const float* arow = emb + (size_t)tok * E_ + lg * 8;

  f32x4 acc[4] = {};
  for (int kt = 0; kt < 8; ++kt){
    short8 af = ld8f_bf(arow + kt * 32);
    #pragma unroll
    for (int g = 0; g < 4; ++g){
      const int j = n0 + g * 16 + l15;
      short8 bw = ld8f_bf(w_ih1 + (size_t)j * E_ + kt * 32 + lg * 8);
      acc[g] = mfma16(af, bw, acc[g]);
    }
  }
  #pragma unroll
  for (int g = 0; g < 4; ++g){
    const int j = n0 + g * 16 + l15;
    const float bias = b_ih1[j] + b_hh1[j];
    const int rr = mt * 16 + lg * 4;
    #pragma unroll
    for (int reg = 0; reg < 4; ++reg)
      xW1[(size_t)(rr + reg) * G4 + j] = acc[g][reg] + bias;
  }
}

// -------------------------------------------------- persistent recurrence
// 64 blocks: 0..31 layer1 (u-slice 16), 32..63 layer2 (u-slice 16).
// Pipelined: iter it -> L1 computes step it, L2 computes step it-1.
// Weights live in VGPRs (one gate per wave); c-state lives in registers.
__global__ __launch_bounds__(256, 1) void k_rnn(
    const float* __restrict__ xW1,
    const float* __restrict__ w_hh1, const float* __restrict__ w_ih2,
    const float* __restrict__ w_hh2,
    const float* __restrict__ b_ih2, const float* __restrict__ b_hh2,
    const float* __restrict__ cnn,
    short* __restrict__ h1buf, short* __restrict__ h2all)
{
  __shared__ float gx[4][32][18];        // [gate][batch][u], padded stride
  const int bid = blockIdx.x;
  const bool isL1 = (bid < 32);
  const int u0 = (isL1 ? bid : bid - 32) * 16;
  const int w = threadIdx.x >> 6;        // wave == gate index
  const int lane = threadIdx.x & 63;
  const int l15 = lane & 15, lg = lane >> 4;
  const int cb = threadIdx.x >> 4;       // cell-phase batch (0..15)
  const int cu = threadIdx.x & 15;       // cell-phase u within slice

  // ---- one-time: weight fragments into VGPRs (gate w, rows u0+l15)
  short8 wA[16], wB[16];
  {
    const float* W0 = isL1 ? w_hh1 : w_ih2;
    const float* b0 = W0 + ((size_t)(w * H_ + u0 + l15)) * H_ + lg * 8;
    #pragma unroll
    for (int kt = 0; kt < 16; ++kt) wA[kt] = ld8f_bf(b0 + kt * 32);
    if (!isL1){
      const float* b1 = w_hh2 + ((size_t)(w * H_ + u0 + l15)) * H_ + lg * 8;
      #pragma unroll
      for (int kt = 0; kt < 16; ++kt) wB[kt] = ld8f_bf(b1 + kt * 32);
    } else {
      #pragma unroll
      for (int kt = 0; kt < 16; ++kt) wB[kt] = short8{0,0,0,0,0,0,0,0};
    }
  }

  float c_a, c_b, bias2[4];
  if (isL1){
    c_a = cnn[cb * H_ + u0 + cu];
    c_b = cnn[(cb + 16) * H_ + u0 + cu];
    bias2[0]=bias2[1]=bias2[2]=bias2[3]=0.f;
  } else {
    c_a = 0.f; c_b = 0.f;
    #pragma unroll
    for (int g = 0; g < 4; ++g)
      bias2[g] = b_ih2[g * H_ + u0 + cu] + b_hh2[g * H_ + u0 + cu];
  }

  cg::grid_group grid = cg::this_grid();

  for (int it = 0; it <= L_; ++it){
    if (isL1 ? (it < L_) : (it >= 1)){
      const int s = isL1 ? it : it - 1;            // step this block computes
      const short* h1r = h1buf + ((it + 1) & 1) * (B_ * H_);  // h1[it-1]
      float add_a[4] = {0.f,0.f,0.f,0.f}, add_b[4] = {0.f,0.f,0.f,0.f};
      if (isL1){
        const float* xr = xW1 + ((size_t)(s * B_ + cb)) * G4 + u0 + cu;
        #pragma unroll
        for (int g = 0; g < 4; ++g){
          add_a[g] = xr[(size_t)g * H_];
          add_b[g] = xr[(size_t)g * H_ + (size_t)16 * G4];
        }
      } else {
        #pragma unroll
        for (int g = 0; g < 4; ++g){ add_a[g] = bias2[g]; add_b[g] = bias2[g]; }
      }

      f32x4 acc0 = {0.f,0.f,0.f,0.f}, acc1 = {0.f,0.f,0.f,0.f};
      #pragma unroll
      for (int kt = 0; kt < 16; ++kt){
        const int k0 = kt * 32 + lg * 8;
        short8 a0 = *(const short8*)(h1r + l15 * H_ + k0);
        short8 a1 = *(const short8*)(h1r + (l15 + 16) * H_ + k0);
        acc0 = mfma16(a0, wA[kt], acc0);
        acc1 = mfma16(a1, wA[kt], acc1);
      }
      if (!isL1 && s >= 1){
        const short* h2r = h2all + (size_t)(s - 1) * H_;   // row b*L + (s-1)
        #pragma unroll
        for (int kt = 0; kt < 16; ++kt){
          const int k0 = kt * 32 + lg * 8;
          short8 a0 = *(const short8*)(h2r + (size_t)l15 * (L_ * H_) + k0);
          short8 a1 = *(const short8*)(h2r + (size_t)(l15 + 16) * (L_ * H_) + k0);
          acc0 = mfma16(a0, wB[kt], acc0);
          acc1 = mfma16(a1, wB[kt], acc1);
        }
      }
      #pragma unroll
      for (int r = 0; r < 4; ++r){
        gx[w][lg * 4 + r][l15]      = acc0[r];
        gx[w][lg * 4 + r + 16][l15] = acc1[r];
      }
      __syncthreads();
      float ga[4], gb[4];
      #pragma unroll
      for (int g = 0; g < 4; ++g){
        ga[g] = gx[g][cb][cu]      + add_a[g];
        gb[g] = gx[g][cb + 16][cu] + add_b[g];
      }
      c_a = sigm(ga[1]) * c_a + sigm(ga[0]) * tanh_f(ga[2]);
      float ha = sigm(ga[3]) * tanh_f(c_a);
      c_b = sigm(gb[1]) * c_b + sigm(gb[0]) * tanh_f(gb[2]);
      float hb = sigm(gb[3]) * tanh_f(c_b);
      if (isL1){
        short* h1w = h1buf + (it & 1) * (B_ * H_);
        h1w[cb * H_ + u0 + cu]        = f2bf(ha);
        h1w[(cb + 16) * H_ + u0 + cu] = f2bf(hb);
      } else {
        h2all[((size_t)cb * L_ + s) * H_ + u0 + cu]        = f2bf(ha);
        h2all[((size_t)(cb + 16) * L_ + s) * H_ + u0 + cu] = f2bf(hb);
      }
    }
    grid.sync();
  }
}

// ----------------------------- logits = h2_all @ w_out^T + b_out, + expsum
// grid (32 mtiles, 250 ntiles); 128x128 tile, BK=64, XOR-swizzled LDS
template<bool PRE>
__global__ __launch_bounds__(256) void k_gemm_out(
    const short* __restrict__ h2all, const short* __restrict__ wob,
    const float* __restrict__ wout, const float* __restrict__ b_out,
    float* __restrict__ out, float* __restrict__ row_sum)
{
  __shared__ __align__(16) short As[128 * 64];
  __shared__ __align__(16) short Bs[128 * 64];
  const int r0 = blockIdx.x * 128, n0 = blockIdx.y * 128;
  const int tid = threadIdx.x;
  const int w = tid >> 6, lane = tid & 63, l15 = lane & 15, lg = lane >> 4;
  const int mrow0 = (w >> 1) * 64, ncol0 = (w & 1) * 64;

  f32x4 acc[4][4] = {};

  for (int kt = 0; kt < 8; ++kt){
    const int kg = kt * 64;
    #pragma unroll
    for (int i = 0; i < 4; ++i){
      const int id = i * 256 + tid;
      const int row = id >> 3, c = id & 7;
      const int cs = c ^ (row & 7);
      *(short8*)(As + row * 64 + cs * 8) =
          *(const short8*)(h2all + (size_t)(r0 + row) * H_ + kg + c * 8);
      if (PRE)
        *(short8*)(Bs + row * 64 + cs * 8) =
            *(const short8*)(wob + (size_t)(n0 + row) * H_ + kg + c * 8);
      else
        *(short8*)(Bs + row * 64 + cs * 8) =
            ld8f_bf(wout + (size_t)(n0 + row) * H_ + kg + c * 8);
    }
    __syncthreads();
    #pragma unroll
    for (int ks = 0; ks < 2; ++ks){
      short8 af[4], bfr[4];
      #pragma unroll
      for (int i = 0; i < 4; ++i){
        const int ra = mrow0 + i * 16 + l15;
        af[i]  = *(const short8*)(As + ra * 64 + (((ks * 4 + lg) ^ (ra & 7)) * 8));
        const int rb = ncol0 + i * 16 + l15;
        bfr[i] = *(const short8*)(Bs + rb * 64 + (((ks * 4 + lg) ^ (rb & 7)) * 8));
      }
      #pragma unroll
      for (int mi = 0; mi < 4; ++mi)
        #pragma unroll
        for (int nj = 0; nj < 4; ++nj)
          acc[mi][nj] = mfma16(af[mi], bfr[nj], acc[mi][nj]);
    }
    __syncthreads();
  }

  float bo[4];
  #pragma unroll
  for (int nj = 0; nj < 4; ++nj) bo[nj] = b_out[n0 + ncol0 + nj * 16 + l15];

  #pragma unroll
  for (int mi = 0; mi < 4; ++mi){
    #pragma unroll
    for (int reg = 0; reg < 4; ++reg){
      const int r = r0 + mrow0 + mi * 16 + lg * 4 + reg;   // = b*L + t
      float* orow = out + (size_t)r * V_;
      float esum = 0.f;
      #pragma unroll
      for (int nj = 0; nj < 4; ++nj){
        float logit = acc[mi][nj][reg] + bo[nj];
        orow[n0 + ncol0 + nj * 16 + l15] = logit;
        esum += __expf(logit);
      }
      esum += __shfl_xor(esum, 1);
      esum += __shfl_xor(esum, 2);
      esum += __shfl_xor(esum, 4);
      esum += __shfl_xor(esum, 8);
      if (l15 == 0) atomicAdd(&row_sum[r], esum);
    }
  }
}

__global__ void k_lse(float* row_sum){
  int i = blockIdx.x * blockDim.x + threadIdx.x;
  if (i < B_ * L_) row_sum[i] = __logf(row_sum[i]);
}

__global__ void k_fix(float* __restrict__ out, const float* __restrict__ lse){
  const size_t stride = (size_t)gridDim.x * blockDim.x;
  const size_t nvec = (size_t)B_ * L_ * V_ / 4;
  for (size_t i = (size_t)blockIdx.x * blockDim.x + threadIdx.x; i < nvec; i += stride){
    const int orow = (int)(i / (V_ / 4));     // = b*128 + t (matches out rows)
    const float l = lse[orow];
    f32x4 v = ((const f32x4*)out)[i];
    v[0] -= l; v[1] -= l; v[2] -= l; v[3] -= l;
    ((f32x4*)out)[i] = v;
  }
}

// ---------------------------------------------------------------- host
extern "C" void kernel_launch(void* const* d_in, const int* in_sizes, int n_in,
                              void* d_out, int out_size, void* d_ws, size_t ws_size,
                              hipStream_t stream)
{
  (void)in_sizes; (void)n_in; (void)out_size;
  const float* cnn   = (const float*)d_in[0];
  const float* emb   = (const float*)d_in[1];
  const float* w_ih1 = (const float*)d_in[2];
  const float* w_hh1 = (const float*)d_in[3];
  const float* b_ih1 = (const float*)d_in[4];
  const float* b_hh1 = (const float*)d_in[5];
  const float* w_ih2 = (const float*)d_in[6];
  const float* w_hh2 = (const float*)d_in[7];
  const float* b_ih2 = (const float*)d_in[8];
  const float* b_hh2 = (const float*)d_in[9];
  const float* w_out = (const float*)d_in[10];
  const float* b_out = (const float*)d_in[11];
  const int*   gt    = (const int*)d_in[12];
  float* out = (float*)d_out;

  char* p = (char*)d_ws;
  size_t off = 0;
  auto carve = [&](size_t bytes)->char* {
    char* q = p + off; off = (off + bytes + 255) & ~(size_t)255; return q;
  };
  short* h2all = (short*)carve(4194304);     // (B*L, H) bf16, row = b*L + t
  short* h1buf = (short*)carve(65536);       // double-buffered h1, bf16
  float* lse   = (float*)carve(16384);       // row expsum -> log-sum-exp
  short* wob   = nullptr;                    // w_out bf16 precast
  float* xW1   = (float*)out;                // fallback scratch (consumed pre-gemm)
  if (ws_size >= off + 33554432ull + 256ull) wob = (short*)carve(33554432);
  if (ws_size >= off + 33554432ull + 256ull) xW1 = (float*)carve(33554432);

  hipLaunchKernelGGL(k_init, dim3(2048), dim3(256), 0, stream, w_out, wob, h1buf, lse);
  hipLaunchKernelGGL(k_xw1, dim3(2048), dim3(256), 0, stream,
                     gt, emb, w_ih1, b_ih1, b_hh1, xW1);

  const float* xW1c = xW1;
  void* args[9];
  args[0] = (void*)&xW1c;
  args[1] = (void*)&w_hh1;
  args[2] = (void*)&w_ih2;
  args[3] = (void*)&w_hh2;
  args[4] = (void*)&b_ih2;
  args[5] = (void*)&b_hh2;
  args[6] = (void*)&cnn;
  args[7] = (void*)&h1buf;
  args[8] = (void*)&h2all;
  hipLaunchCooperativeKernel(reinterpret_cast<void*>(k_rnn), dim3(64), dim3(256),
                             args, 0, stream);

  if (wob)
    hipLaunchKernelGGL(HIP_KERNEL_NAME(k_gemm_out<true>), dim3(32, 250), dim3(256), 0, stream,
                       h2all, wob, w_out, b_out, out, lse);
  else
    hipLaunchKernelGGL(HIP_KERNEL_NAME(k_gemm_out<false>), dim3(32, 250), dim3(256), 0, stream,
                       h2all, wob, w_out, b_out, out, lse);
  hipLaunchKernelGGL(k_lse, dim3(16), dim3(256), 0, stream, lse);
  hipLaunchKernelGGL(k_fix, dim3(2048), dim3(256), 0, stream, out, lse);
}